// Round 1
// 577.622 us; speedup vs baseline: 1.0049x; 1.0049x over previous
//
#include <hip/hip_runtime.h>

#define D 64
#define P 20            // NUM_PROTO
#define ROWS_PER_BLOCK 4

// One wave (64 lanes) per row n.
// - Gather loads (HBM-heavy, ~900-cyc miss) are issued FIRST so their latency
//   overlaps the matvec phase.
// - The x row is wave-uniform: readfirstlane forces the compiler to prove it,
//   so the x reads go out on the scalar (SMEM) pipe. No LDS staging, no
//   __syncthreads -- the 4 waves in the block are fully decoupled.
// - W row per lane (256 B) is L1-hot across all 16384 waves; z never leaves
//   registers (wave shuffles only).
__global__ __launch_bounds__(256) void user_memory_fused(
    const int*   __restrict__ uidx,
    const float* __restrict__ x,
    const float* __restrict__ proto,
    const float* __restrict__ W,
    const float* __restrict__ bias,
    float*       __restrict__ out,
    int n_rows)
{
    const int wave = threadIdx.x >> 6;
    const int lane = threadIdx.x & 63;
    int row = blockIdx.x * ROWS_PER_BLOCK + wave;
    if (row >= n_rows) return;   // exact for N % ROWS_PER_BLOCK == 0
    // row is the same value in every lane of the wave; make that provable so
    // uidx/x loads scalarize (s_load) instead of going through VMEM/LDS.
    row = __builtin_amdgcn_readfirstlane(row);

    // ---- issue the anchor gather immediately (depends only on uidx) ----
    const int u = uidx[row];                      // uniform -> s_load_dword
    const float4* ap = (const float4*)(proto + (size_t)u * (P * D)) + lane;
    float4 av0 = ap[0];      // wave reads 5 x 1KiB, fully coalesced
    float4 av1 = ap[64];
    float4 av2 = ap[128];
    float4 av3 = ap[192];
    float4 av4 = ap[256];

    // ---- matvec: h[lane] = W[lane,:] . x[row,:] + b[lane] ----
    float acc = bias[lane];
    const float4* wrow = (const float4*)(W + lane * D);      // per-lane, L1-hot
    const float4* xr   = (const float4*)(x + (size_t)row * D); // uniform -> SMEM
#pragma unroll
    for (int k = 0; k < D / 4; ++k) {
        float4 wv = wrow[k];
        float4 xk = xr[k];
        acc += wv.x * xk.x + wv.y * xk.y + wv.z * xk.z + wv.w * xk.w;
    }

    // ||h||^2 across the wave; z[lane] stays in-register
    float s = acc * acc;
#pragma unroll
    for (int off = 32; off >= 1; off >>= 1) s += __shfl_xor(s, off);
    float z = acc * (1.0f / fmaxf(sqrtf(s), 1e-12f));

    // lane needs z[4*(lane&15) .. +3] — 4 shuffles, no LDS/barrier
    const int zb = (lane & 15) * 4;
    float4 zv;
    zv.x = __shfl(z, zb + 0);
    zv.y = __shfl(z, zb + 1);
    zv.z = __shfl(z, zb + 2);
    zv.w = __shfl(z, zb + 3);

    // ---- consume prefetched anchors: normalize + dot over 20 protos ----
    // Layout: av{it} covers protos 4*it .. 4*it+3; the 16-lane group
    // (lane>>4) within the wave owns proto 4*it + (lane>>4), holding
    // d = 4*(lane&15) .. +3.
    float cacc = 0.0f;
    float4 avs[5] = {av0, av1, av2, av3, av4};
#pragma unroll
    for (int it = 0; it < 5; ++it) {
        float4 av = avs[it];
        float s2 = av.x * av.x + av.y * av.y + av.z * av.z + av.w * av.w;
        float dt = av.x * zv.x + av.y * zv.y + av.z * zv.z + av.w * zv.w;
#pragma unroll
        for (int off = 1; off <= 8; off <<= 1) {   // reduce within 16-lane group
            s2 += __shfl_xor(s2, off);
            dt += __shfl_xor(dt, off);
        }
        cacc += dt * __frsqrt_rn(fmaxf(s2, 1e-24f));   // dt / max(||a||, 1e-12)
    }

    // four 16-lane groups hold identical partials; xor 16 & 32 combine them
    cacc += __shfl_xor(cacc, 16);
    cacc += __shfl_xor(cacc, 32);
    if (lane == 0) out[row] = cacc;
}

extern "C" void kernel_launch(void* const* d_in, const int* in_sizes, int n_in,
                              void* d_out, int out_size, void* d_ws, size_t ws_size,
                              hipStream_t stream) {
    const int*   uidx  = (const int*)d_in[0];
    const float* x     = (const float*)d_in[1];
    const float* proto = (const float*)d_in[2];
    const float* W     = (const float*)d_in[3];
    const float* bias  = (const float*)d_in[4];
    float*       out   = (float*)d_out;

    const int n = in_sizes[0];
    const int blocks = (n + ROWS_PER_BLOCK - 1) / ROWS_PER_BLOCK;
    hipLaunchKernelGGL(user_memory_fused, dim3(blocks), dim3(256), 0, stream,
                       uidx, x, proto, W, bias, out, n);
}